// Round 19
// baseline (749.837 us; speedup 1.0000x reference)
//
#include <hip/hip_runtime.h>
#include <hip/hip_bf16.h>

// Problem constants
#define NTOK   32768          // 32 * 1024 tokens
#define BATCH  32
#define SEQ    1024
#define DIMD   768
#define HEADS  12
#define HDIM   64
#define MFEAT  384
#define HIDDEN 3072
#define SCALE  0.35355339059327379f   // 64^-0.25
#define HALF_SCALE2 0.0625f           // 0.5 * SCALE^2
#define EPSP   3.84e-6f               // 1e-8 / RSM^2 (RSM factors cancel in out)
#define WSCL   64.0f                  // fp8 weight pre-scale (absorbed by MX B-scale 2^-6)
#define SCA_ONE   0x7F7F7F7Fu         // e8m0 1.0
#define SCB_I64   0x79797979u         // e8m0 2^-6 = 1/64

typedef __attribute__((ext_vector_type(8))) short bf16x8;
typedef __attribute__((ext_vector_type(4))) float f32x4;
typedef __attribute__((ext_vector_type(2))) long long llong2;
typedef __attribute__((ext_vector_type(8))) int i32x8;

static __device__ __forceinline__ float bf2f(unsigned short u) {
    return __uint_as_float(((unsigned)u) << 16);
}
static __device__ __forceinline__ unsigned short f2bf(float f) {
    unsigned u = __float_as_uint(f);
    return (unsigned short)((u + 0x7FFFu + ((u >> 16) & 1u)) >> 16);  // RNE
}
// pack 4 f32 -> 4 bf16 (8B) via v_cvt_pk_bf16_f32 (compiler-generated, RNE)
static __device__ __forceinline__ uint2 pk4bf(float e0, float e1, float e2, float e3) {
    const __hip_bfloat162 lo = __float22bfloat162_rn(make_float2(e0, e1));
    const __hip_bfloat162 hi = __float22bfloat162_rn(make_float2(e2, e3));
    uint2 r;
    r.x = *(const unsigned*)&lo;
    r.y = *(const unsigned*)&hi;
    return r;
}
// f32 -> OCP e4m3fn, RNE, saturate (software path; off critical path)
static __device__ __forceinline__ unsigned char f2e4m3(float f) {
    unsigned u = __float_as_uint(f);
    const unsigned char s = (unsigned char)((u >> 24) & 0x80);
    const float af = __uint_as_float(u & 0x7FFFFFFF);
    if (!(af < 464.0f)) return s | 0x7E;                 // saturate (448)
    int e = (int)((u >> 23) & 0xFF) - 127;
    if (e < -6) e = -6;
    const float ulp = __uint_as_float((unsigned)((e - 3 + 127) << 23));  // 2^(e-3)
    const float q = rintf(af / ulp) * ulp;               // RNE quantize
    if (q == 0.0f) return s;
    const unsigned v = __float_as_uint(q);
    const int qe = (int)((v >> 23) & 0xFF) - 127;
    if (qe < -6) return s | (unsigned char)(q * 512.0f); // subnormal m*2^-9
    return s | (unsigned char)(((qe + 7) << 3) | ((v >> 20) & 7));
}
// hardware f32 -> fp8 e4m3 (gfx950 OCP), 1 VALU op
static __device__ __forceinline__ unsigned char f2e4m3_hw(float v) {
    unsigned r = 0;
    asm("v_cvt_pk_fp8_f32 %0, %1, %1" : "+v"(r) : "v"(v));
    return (unsigned char)(r & 0xFF);
}
// MX byte permutation within each 128-k group (fp8 path)
static __device__ __forceinline__ int kp128(int kl) {   // kl in [0,128)
    return (((kl >> 4) & 1) << 6) + ((kl >> 5) << 4) + (kl & 15);
}
// gelu tanh-approx, exp form with hw rcp
static __device__ __forceinline__ float gelu_fast(float v) {
    const float c = 0.7978845608028654f;
    const float u = c * v * (1.0f + 0.044715f * v * v);
    return v * __builtin_amdgcn_rcpf(1.0f + __expf(-2.0f * u));
}
static __device__ __forceinline__ void gload16(const void* g, void* l) {
    __builtin_amdgcn_global_load_lds(
        (const __attribute__((address_space(1))) void*)g,
        (__attribute__((address_space(3))) void*)l, 16, 0, 0);
}

// ---------------- vectorized LayerNorm; OT: 1 = bf16 out, 2 = fp8 out (kp128)
template <int OT>
__global__ __launch_bounds__(256) void ln_vec(
    const float* __restrict__ x, const float* __restrict__ g,
    const float* __restrict__ bta, void* __restrict__ o) {
    const size_t row = blockIdx.x;
    const float* xr = x + row * DIMD;
    const int t = threadIdx.x;
    float4 v = make_float4(0.f, 0.f, 0.f, 0.f);
    if (t < 192) v = *(const float4*)(xr + t * 4);
    float s  = v.x + v.y + v.z + v.w;
    float sq = v.x * v.x + v.y * v.y + v.z * v.z + v.w * v.w;
    const int lane = t & 63, w = t >> 6;
    #pragma unroll
    for (int off = 32; off > 0; off >>= 1) {
        s  += __shfl_down(s, off, 64);
        sq += __shfl_down(sq, off, 64);
    }
    __shared__ float red[2][4];
    if (lane == 0) { red[0][w] = s; red[1][w] = sq; }
    __syncthreads();
    s  = red[0][0] + red[0][1] + red[0][2] + red[0][3];
    sq = red[1][0] + red[1][1] + red[1][2] + red[1][3];
    const float mu  = s * (1.0f / DIMD);
    const float var = sq * (1.0f / DIMD) - mu * mu;
    const float r = rsqrtf(var + 1e-5f);
    if (t < 192) {
        const float4 gv = *(const float4*)(g + t * 4);
        const float4 bv = *(const float4*)(bta + t * 4);
        const float o0 = (v.x - mu) * r * gv.x + bv.x;
        const float o1 = (v.y - mu) * r * gv.y + bv.y;
        const float o2 = (v.z - mu) * r * gv.z + bv.z;
        const float o3 = (v.w - mu) * r * gv.w + bv.w;
        if constexpr (OT == 1) {
            unsigned short* orow = (unsigned short*)o + row * DIMD + t * 4;
            *(ushort4*)orow = make_ushort4(f2bf(o0), f2bf(o1), f2bf(o2), f2bf(o3));
        } else {
            const int k = t * 4;
            const int gb = k & ~127, kl = k & 127;
            unsigned char* orow = (unsigned char*)o + row * DIMD + gb + kp128(kl);
            uchar4 p; p.x = f2e4m3(o0); p.y = f2e4m3(o1);
            p.z = f2e4m3(o2); p.w = f2e4m3(o3);
            *(uchar4*)orow = p;
        }
    }
}

// ---------------- weight convert + transpose: W[K,N] f32 -> Wt[N,K] bf16 ---
__global__ __launch_bounds__(256) void wconv(
    const float* __restrict__ W, unsigned short* __restrict__ Wt, int K, int N) {
    __shared__ float tile[32][33];
    const int n0 = blockIdx.x << 5, k0 = blockIdx.y << 5;
    const int tn = threadIdx.x & 31, tg = threadIdx.x >> 5;
    #pragma unroll
    for (int i = 0; i < 4; ++i) {
        const int k = (tg << 2) + i;
        tile[k][tn] = W[(size_t)(k0 + k) * N + n0 + tn];
    }
    __syncthreads();
    #pragma unroll
    for (int i = 0; i < 4; ++i) {
        const int n = (tg << 2) + i;
        Wt[(size_t)(n0 + n) * K + k0 + tn] = f2bf(tile[tn][n]);
    }
}

// ---------------- weight convert: W[K,N] f32 -> Wt[N,K] fp8 (x64, kp128) ---
__global__ __launch_bounds__(256) void wconv_f8(
    const float* __restrict__ W, unsigned char* __restrict__ Wt, int K, int N) {
    __shared__ float tile[32][33];
    const int n0 = blockIdx.x << 5, k0 = blockIdx.y << 5;
    const int tn = threadIdx.x & 31, tg = threadIdx.x >> 5;
    #pragma unroll
    for (int i = 0; i < 4; ++i) {
        const int k = (tg << 2) + i;
        tile[k][tn] = W[(size_t)(k0 + k) * N + n0 + tn];
    }
    __syncthreads();
    #pragma unroll
    for (int i = 0; i < 4; ++i) {
        const int n = (tg << 2) + i;
        const int k = k0 + tn;
        const int gb = k & ~127, kl = k & 127;
        Wt[(size_t)(n0 + n) * K + gb + kp128(kl)] = f2e4m3(WSCL * tile[tn][n]);
    }
}

// ---------------- worf prep: worf_ts[h][m][c] = bf16(SCALE * worf[h][c][m])
__global__ __launch_bounds__(256) void wprep(
    const float* __restrict__ worf, unsigned short* __restrict__ worf_ts) {
    __shared__ float tile[32][33];
    const int m0 = blockIdx.x << 5, c0 = blockIdx.y << 5, h = blockIdx.z;
    const int tn = threadIdx.x & 31, tg = threadIdx.x >> 5;
    #pragma unroll
    for (int i = 0; i < 4; ++i) {
        const int c = (tg << 2) + i;
        tile[c][tn] = worf[(size_t)(h * HDIM + c0 + c) * MFEAT + m0 + tn];
    }
    __syncthreads();
    #pragma unroll
    for (int i = 0; i < 4; ++i) {
        const int m = (tg << 2) + i;
        worf_ts[(size_t)(h * MFEAT + m0 + m) * HDIM + c0 + tn] =
            f2bf(SCALE * tile[tn][m]);
    }
}

// ---------------- bf16 GEMM BK=64 S0/S1 (round-17 measured best for qkv) ---
template <int ACT, bool RES, bool OBF16>
__global__ __launch_bounds__(256, 2) void gemm_bk64(
    const unsigned short* __restrict__ A, const unsigned short* __restrict__ Wt,
    const float* __restrict__ bias, const float* __restrict__ resid,
    void* __restrict__ Craw, int K, int N) {
    __shared__ unsigned short As0[2][4096], As1[2][4096];   // 16 KB
    __shared__ unsigned short Bs0[2][4096], Bs1[2][4096];   // 16 KB
    const int t = threadIdx.x;
    const int w = t >> 6, l = t & 63;
    const int ncol = gridDim.x;
    const int lin = blockIdx.y * ncol + blockIdx.x;
    const int cpx = (ncol * gridDim.y) >> 3;
    const int wg = (lin & 7) * cpx + (lin >> 3);
    const int row0 = (wg / ncol) << 7, col0 = (wg % ncol) << 7;
    const int wr = (w >> 1) << 6, wc = (w & 1) << 6;

    const int sc = (((l & 3) ^ ((l >> 3) & 3)) << 3);   // bf16 units in 64B seg
    const size_t arow0 = (size_t)(row0 + w * 32 + (l >> 2)) * K;
    const size_t arow1 = arow0 + (size_t)16 * K;
    const size_t brow0 = (size_t)(col0 + w * 32 + (l >> 2)) * K;
    const size_t brow1 = brow0 + (size_t)16 * K;

    f32x4 acc[4][4] = {};
    const int NT = K >> 6;

    auto stage = [&](int bi, int s) {
        const size_t ko = (size_t)s << 6;   // 64 bf16 per K-step
        gload16(A + arow0 + ko + sc,      &As0[bi][w * 1024]);
        gload16(A + arow1 + ko + sc,      &As0[bi][w * 1024 + 512]);
        gload16(A + arow0 + ko + 32 + sc, &As1[bi][w * 1024]);
        gload16(A + arow1 + ko + 32 + sc, &As1[bi][w * 1024 + 512]);
        gload16(Wt + brow0 + ko + sc,      &Bs0[bi][w * 1024]);
        gload16(Wt + brow1 + ko + sc,      &Bs0[bi][w * 1024 + 512]);
        gload16(Wt + brow0 + ko + 32 + sc, &Bs1[bi][w * 1024]);
        gload16(Wt + brow1 + ko + 32 + sc, &Bs1[bi][w * 1024 + 512]);
    };

    stage(0, 0);
    const int lr = l & 15, lg = l >> 4;
    const int xoff = ((lg ^ ((lr >> 1) & 3)) << 3);
    for (int s = 0; s < NT; ++s) {
        asm volatile("s_waitcnt vmcnt(0)" ::: "memory");
        __builtin_amdgcn_s_barrier();
        __builtin_amdgcn_sched_barrier(0);
        if (s + 1 < NT) stage((s + 1) & 1, s + 1);
        const unsigned short* a0 = &As0[s & 1][0];
        const unsigned short* a1 = &As1[s & 1][0];
        const unsigned short* b0 = &Bs0[s & 1][0];
        const unsigned short* b1 = &Bs1[s & 1][0];
        bf16x8 af[4][2], bfr[4][2];
        #pragma unroll
        for (int f = 0; f < 4; ++f) {
            const int ra = ((wr + f * 16 + lr) << 5) + xoff;
            const int rb = ((wc + f * 16 + lr) << 5) + xoff;
            af[f][0]  = *(const bf16x8*)(a0 + ra);
            af[f][1]  = *(const bf16x8*)(a1 + ra);
            bfr[f][0] = *(const bf16x8*)(b0 + rb);
            bfr[f][1] = *(const bf16x8*)(b1 + rb);
        }
        #pragma unroll
        for (int ks = 0; ks < 2; ++ks)
            #pragma unroll
            for (int fi = 0; fi < 4; ++fi)
                #pragma unroll
                for (int fj = 0; fj < 4; ++fj)
                    acc[fi][fj] = __builtin_amdgcn_mfma_f32_16x16x32_bf16(
                        af[fi][ks], bfr[fj][ks], acc[fi][fj], 0, 0, 0);
    }

    float bv[4];
    #pragma unroll
    for (int fj = 0; fj < 4; ++fj) bv[fj] = bias[col0 + wc + fj * 16 + lr];
    #pragma unroll
    for (int fi = 0; fi < 4; ++fi) {
        #pragma unroll
        for (int r = 0; r < 4; ++r) {
            const int row = row0 + wr + fi * 16 + lg * 4 + r;
            const size_t base = (size_t)row * N + col0 + wc + lr;
            #pragma unroll
            for (int fj = 0; fj < 4; ++fj) {
                float v = acc[fi][fj][r] + bv[fj];
                if constexpr (RES) v += resid[base + fj * 16];
                if constexpr (ACT == 1) v = gelu_fast(v);
                if constexpr (OBF16) ((unsigned short*)Craw)[base + fj * 16] = f2bf(v);
                else                 ((float*)Craw)[base + fj * 16] = v;
            }
        }
    }
}

// ---------------- bf16 GEMM BK=32 3-buf (round-16 proven, for proj) --------
template <int ACT, bool RES, bool OBF16>
__global__ __launch_bounds__(256, 2) void gemm_bk32(
    const unsigned short* __restrict__ A, const unsigned short* __restrict__ Wt,
    const float* __restrict__ bias, const float* __restrict__ resid,
    void* __restrict__ Craw, int K, int N) {
    __shared__ unsigned short As[3][128 * 32];
    __shared__ unsigned short Bs[3][128 * 32];
    const int t = threadIdx.x;
    const int w = t >> 6, l = t & 63;
    const int ncol = gridDim.x;
    const int lin = blockIdx.y * ncol + blockIdx.x;
    const int cpx = (ncol * gridDim.y) >> 3;
    const int wg = (lin & 7) * cpx + (lin >> 3);
    const int row0 = (wg / ncol) << 7, col0 = (wg % ncol) << 7;
    const int wr = (w >> 1) << 6, wc = (w & 1) << 6;

    const int sc = (((l & 3) ^ ((l >> 3) & 3)) << 3);
    const unsigned short* ag0 = A  + (size_t)(row0 + w * 32 + (l >> 2)) * K + sc;
    const unsigned short* ag1 = ag0 + (size_t)16 * K;
    const unsigned short* bg0 = Wt + (size_t)(col0 + w * 32 + (l >> 2)) * K + sc;
    const unsigned short* bg1 = bg0 + (size_t)16 * K;

    f32x4 acc[4][4] = {};
    const int NT = K >> 5;

    auto stage = [&](int bi, int s) {
        const size_t ko = (size_t)s << 5;
        gload16(ag0 + ko, &As[bi][w * 1024]);
        gload16(ag1 + ko, &As[bi][w * 1024 + 512]);
        gload16(bg0 + ko, &Bs[bi][w * 1024]);
        gload16(bg1 + ko, &Bs[bi][w * 1024 + 512]);
    };

    stage(0, 0);
    stage(1, 1);
    const int lr = l & 15, lg = l >> 4;
    const int lkx = (lg << 3) ^ ((((lr >> 1) & 3)) << 3);
    int cur = 0;
    for (int s = 0; s < NT; ++s) {
        if (s + 1 < NT) asm volatile("s_waitcnt vmcnt(4)" ::: "memory");
        else            asm volatile("s_waitcnt vmcnt(0)" ::: "memory");
        __builtin_amdgcn_s_barrier();
        __builtin_amdgcn_sched_barrier(0);
        if (s + 2 < NT) {
            int sb = cur + 2; if (sb >= 3) sb -= 3;
            stage(sb, s + 2);
        }
        const unsigned short* ab = &As[cur][0];
        const unsigned short* bb = &Bs[cur][0];
        bf16x8 af[4], bfr[4];
        #pragma unroll
        for (int f = 0; f < 4; ++f) {
            af[f]  = *(const bf16x8*)(ab + (wr + f * 16 + lr) * 32 + lkx);
            bfr[f] = *(const bf16x8*)(bb + (wc + f * 16 + lr) * 32 + lkx);
        }
        #pragma unroll
        for (int fi = 0; fi < 4; ++fi)
            #pragma unroll
            for (int fj = 0; fj < 4; ++fj)
                acc[fi][fj] = __builtin_amdgcn_mfma_f32_16x16x32_bf16(
                    af[fi], bfr[fj], acc[fi][fj], 0, 0, 0);
        cur = (cur + 1 == 3) ? 0 : cur + 1;
    }

    float bv[4];
    #pragma unroll
    for (int fj = 0; fj < 4; ++fj) bv[fj] = bias[col0 + wc + fj * 16 + lr];
    #pragma unroll
    for (int fi = 0; fi < 4; ++fi) {
        #pragma unroll
        for (int r = 0; r < 4; ++r) {
            const int row = row0 + wr + fi * 16 + lg * 4 + r;
            const size_t base = (size_t)row * N + col0 + wc + lr;
            #pragma unroll
            for (int fj = 0; fj < 4; ++fj) {
                float v = acc[fi][fj][r] + bv[fj];
                if constexpr (RES) v += resid[base + fj * 16];
                if constexpr (ACT == 1) v = gelu_fast(v);
                if constexpr (OBF16) ((unsigned short*)Craw)[base + fj * 16] = f2bf(v);
                else                 ((float*)Craw)[base + fj * 16] = v;
            }
        }
    }
}

// ---------------- MX-fp8 MFMA GEMM (round-16 proven): fc1 + fc2 ------------
template <int ACT, bool RES, int OT>
__global__ __launch_bounds__(256, 2) void gemm_mx(
    const unsigned char* __restrict__ A, const unsigned char* __restrict__ Wt,
    const float* __restrict__ bias, const float* __restrict__ resid,
    void* __restrict__ Craw, int K, int N) {
    __shared__ unsigned char As0[2][8192], As1[2][8192];   // 32 KB
    __shared__ unsigned char Bs0[2][8192], Bs1[2][8192];   // 32 KB
    const int t = threadIdx.x;
    const int w = t >> 6, l = t & 63;
    const int ncol = gridDim.x;
    const int lin = blockIdx.y * ncol + blockIdx.x;
    const int cpx = (ncol * gridDim.y) >> 3;
    const int wg = (lin & 7) * cpx + (lin >> 3);
    const int row0 = (wg / ncol) << 7, col0 = (wg % ncol) << 7;
    const int wr = (w >> 1) << 6, wc = (w & 1) << 6;

    const int sc = (((l & 3) ^ ((l >> 3) & 3)) << 4);
    const size_t arow0 = (size_t)(row0 + w * 32 + (l >> 2)) * K;
    const size_t arow1 = arow0 + (size_t)16 * K;
    const size_t brow0 = (size_t)(col0 + w * 32 + (l >> 2)) * K;
    const size_t brow1 = brow0 + (size_t)16 * K;

    f32x4 acc[4][4] = {};
    const int NT = K >> 7;

    auto stage = [&](int bi, int s) {
        const size_t ko = (size_t)s << 7;
        gload16(A + arow0 + ko + sc,      &As0[bi][w * 2048]);
        gload16(A + arow1 + ko + sc,      &As0[bi][w * 2048 + 1024]);
        gload16(A + arow0 + ko + 64 + sc, &As1[bi][w * 2048]);
        gload16(A + arow1 + ko + 64 + sc, &As1[bi][w * 2048 + 1024]);
        gload16(Wt + brow0 + ko + sc,      &Bs0[bi][w * 2048]);
        gload16(Wt + brow1 + ko + sc,      &Bs0[bi][w * 2048 + 1024]);
        gload16(Wt + brow0 + ko + 64 + sc, &Bs1[bi][w * 2048]);
        gload16(Wt + brow1 + ko + 64 + sc, &Bs1[bi][w * 2048 + 1024]);
    };

    stage(0, 0);
    const int lr = l & 15, lg = l >> 4;
    const int xoff = ((lg ^ ((lr >> 1) & 3)) << 4);
    for (int s = 0; s < NT; ++s) {
        asm volatile("s_waitcnt vmcnt(0)" ::: "memory");
        __builtin_amdgcn_s_barrier();
        __builtin_amdgcn_sched_barrier(0);
        if (s + 1 < NT) stage((s + 1) & 1, s + 1);
        const unsigned char* a0 = &As0[s & 1][0];
        const unsigned char* a1 = &As1[s & 1][0];
        const unsigned char* b0 = &Bs0[s & 1][0];
        const unsigned char* b1 = &Bs1[s & 1][0];
        i32x8 afm[4], bfm[4];
        #pragma unroll
        for (int f = 0; f < 4; ++f) {
            const int ra = ((wr + f * 16 + lr) << 6) + xoff;
            const int rb = ((wc + f * 16 + lr) << 6) + xoff;
            ((llong2*)&afm[f])[0] = *(const llong2*)(a0 + ra);
            ((llong2*)&afm[f])[1] = *(const llong2*)(a1 + ra);
            ((llong2*)&bfm[f])[0] = *(const llong2*)(b0 + rb);
            ((llong2*)&bfm[f])[1] = *(const llong2*)(b1 + rb);
        }
        #pragma unroll
        for (int fi = 0; fi < 4; ++fi)
            #pragma unroll
            for (int fj = 0; fj < 4; ++fj)
                acc[fi][fj] = __builtin_amdgcn_mfma_scale_f32_16x16x128_f8f6f4(
                    afm[fi], bfm[fj], acc[fi][fj], 0, 0,
                    0, SCA_ONE, 0, SCB_I64);
    }

    float bv[4];
    #pragma unroll
    for (int fj = 0; fj < 4; ++fj) bv[fj] = bias[col0 + wc + fj * 16 + lr];
    #pragma unroll
    for (int fi = 0; fi < 4; ++fi) {
        #pragma unroll
        for (int r = 0; r < 4; ++r) {
            const int row = row0 + wr + fi * 16 + lg * 4 + r;
            const size_t base = (size_t)row * N + col0 + wc + lr;
            #pragma unroll
            for (int fj = 0; fj < 4; ++fj) {
                float v = acc[fi][fj][r] + bv[fj];
                if constexpr (RES) v += resid[base + fj * 16];
                if constexpr (ACT == 1) v = gelu_fast(v);
                if constexpr (OT == 2) {
                    const int cl = wc + fj * 16 + lr;
                    ((unsigned char*)Craw)[(size_t)row * N + col0 + kp128(cl)] =
                        f2e4m3_hw(v);
                } else {
                    ((float*)Craw)[base + fj * 16] = v;
                }
            }
        }
    }
}

// ---------------- Phase A (MFMA): per (b,h,z): partial ktvT over 512 tokens
// blockIdx.z in {0,1} selects token half; partial bf16 ktvT written to
// ktvT + (z*384 + bh)*80*MFEAT. attn_out merges the two partials.
__global__ __launch_bounds__(256, 1) void ktv_mfma(
    const unsigned short* __restrict__ qkvb,
    const unsigned short* __restrict__ worf_ts,
    unsigned short* __restrict__ ktvT) {
    const int h = blockIdx.x, b = blockIdx.y, z = blockIdx.z;
    const int bh = b * HEADS + h;
    __shared__ __align__(16) unsigned short Klds[32][72];
    __shared__ __align__(16) unsigned short VT[80][40];
    __shared__ __align__(16) unsigned short P[4][96][40];
    const int t = threadIdx.x, w = t >> 6, l = t & 63;
    const int lr = l & 15, lg = l >> 4;
    const int m0 = w * 96;

    bf16x8 bfw[6][2];
    #pragma unroll
    for (int mt = 0; mt < 6; ++mt)
        #pragma unroll
        for (int ks = 0; ks < 2; ++ks)
            bfw[mt][ks] = *(const bf16x8*)(worf_ts +
                (size_t)(h * MFEAT + m0 + mt * 16 + lr) * HDIM + ks * 32 + lg * 8);

    f32x4 acc[5][6] = {};

    for (int i = t; i < 16 * 40; i += 256) {
        const int r = 64 + i / 40, cc = i % 40;
        VT[r][cc] = (r == 64) ? (unsigned short)0x3F80 : (unsigned short)0;
    }
    const unsigned short* kglob = qkvb +
        ((size_t)b * SEQ + z * (SEQ / 2)) * 2304 + 768 + h * 64;
    const unsigned short* vglob = kglob + 768;

    for (int n0 = 0; n0 < SEQ / 2; n0 += 32) {
        __syncthreads();
        {
            const int row = t >> 3, c8 = (t & 7) << 3;
            *(bf16x8*)&Klds[row][c8] =
                *(const bf16x8*)(kglob + (size_t)(n0 + row) * 2304 + c8);
        }
        {
            const int n = t & 31, c0 = (t >> 5) << 3;
            const unsigned short* src = vglob + (size_t)(n0 + n) * 2304 + c0;
            ushort4 v0 = *(const ushort4*)src;
            ushort4 v1 = *(const ushort4*)(src + 4);
            VT[c0 + 0][n] = v0.x; VT[c0 + 1][n] = v0.y;
            VT[c0 + 2][n] = v0.z; VT[c0 + 3][n] = v0.w;
            VT[c0 + 4][n] = v1.x; VT[c0 + 5][n] = v1.y;
            VT[c0 + 6][n] = v1.z; VT[c0 + 7][n] = v1.w;
        }
        __syncthreads();

        bf16x8 afk[2][2];
        float sqv[2][4];
        #pragma unroll
        for (int ns = 0; ns < 2; ++ns) {
            float s = 0.f;
            #pragma unroll
            for (int ks = 0; ks < 2; ++ks) {
                afk[ns][ks] = *(const bf16x8*)&Klds[ns * 16 + lr][ks * 32 + lg * 8];
                #pragma unroll
                for (int j = 0; j < 8; ++j) {
                    const float f = bf2f((unsigned short)afk[ns][ks][j]);
                    s += f * f;
                }
            }
            s += __shfl_xor(s, 16);
            s += __shfl_xor(s, 32);
            s *= HALF_SCALE2;
            #pragma unroll
            for (int r = 0; r < 4; ++r)
                sqv[ns][r] = __shfl(s, (lg << 2) + r);
        }

        #pragma unroll
        for (int mt = 0; mt < 6; ++mt) {
            #pragma unroll
            for (int ns = 0; ns < 2; ++ns) {
                f32x4 p = {};
                p = __builtin_amdgcn_mfma_f32_16x16x32_bf16(afk[ns][0], bfw[mt][0], p, 0, 0, 0);
                p = __builtin_amdgcn_mfma_f32_16x16x32_bf16(afk[ns][1], bfw[mt][1], p, 0, 0, 0);
                const uint2 pk2 = pk4bf(__expf(p[0] - sqv[ns][0]), __expf(p[1] - sqv[ns][1]),
                                        __expf(p[2] - sqv[ns][2]), __expf(p[3] - sqv[ns][3]));
                *(uint2*)&P[w][mt * 16 + lr][ns * 16 + lg * 4] = pk2;
            }
        }
        asm volatile("s_waitcnt lgkmcnt(0)" ::: "memory");
        __builtin_amdgcn_sched_barrier(0);

        bf16x8 afv[5];
        #pragma unroll
        for (int ct = 0; ct < 5; ++ct)
            afv[ct] = *(const bf16x8*)&VT[ct * 16 + lr][lg * 8];
        #pragma unroll
        for (int mt = 0; mt < 6; ++mt) {
            const bf16x8 bp = *(const bf16x8*)&P[w][mt * 16 + lr][lg * 8];
            #pragma unroll
            for (int ct = 0; ct < 5; ++ct)
                acc[ct][mt] = __builtin_amdgcn_mfma_f32_16x16x32_bf16(afv[ct], bp, acc[ct][mt], 0, 0, 0);
        }
    }

    unsigned short* dst = ktvT + (size_t)(z * 384 + bh) * 80 * MFEAT;
    #pragma unroll
    for (int ct = 0; ct < 5; ++ct)
        #pragma unroll
        for (int mt = 0; mt < 6; ++mt)
            #pragma unroll
            for (int r = 0; r < 4; ++r) {
                const int cc = ct * 16 + lg * 4 + r;
                const int m = m0 + mt * 16 + lr;
                dst[(size_t)cc * MFEAT + m] = f2bf(acc[ct][mt][r]);
            }
}

// ---------------- Phase B (MFMA): out^T[c,n] = sum_m (ktvT0+ktvT1)[c,m]*phi
__global__ __launch_bounds__(256) void attn_out_mfma(
    const unsigned short* __restrict__ qkvb,
    const unsigned short* __restrict__ worf_ts,
    const unsigned short* __restrict__ ktvT,
    unsigned short* __restrict__ attn) {
    const int n0 = blockIdx.x << 7;
    const int h = blockIdx.y, b = blockIdx.z, bh = b * HEADS + h;
    __shared__ __align__(16) unsigned short KT[80][104];
    __shared__ __align__(16) unsigned short P[4][32][104];
    const int t = threadIdx.x, w = t >> 6, l = t & 63;
    const int lr = l & 15, lg = l >> 4;
    const int nw = n0 + w * 32;

    bf16x8 bq[2][2];
    float sqn[2];
    #pragma unroll
    for (int nt = 0; nt < 2; ++nt) {
        float s = 0.f;
        #pragma unroll
        for (int ks = 0; ks < 2; ++ks) {
            bq[nt][ks] = *(const bf16x8*)(qkvb +
                (size_t)(b * SEQ + nw + nt * 16 + lr) * 2304 + h * 64 + ks * 32 + lg * 8);
            #pragma unroll
            for (int j = 0; j < 8; ++j) {
                const float f = bf2f((unsigned short)bq[nt][ks][j]);
                s += f * f;
            }
        }
        s += __shfl_xor(s, 16);
        s += __shfl_xor(s, 32);
        sqn[nt] = s * HALF_SCALE2;
    }

    f32x4 acc[5][2] = {};
    const unsigned short* ktg0 = ktvT + (size_t)bh * 80 * MFEAT;
    const unsigned short* ktg1 = ktvT + (size_t)(384 + bh) * 80 * MFEAT;

    for (int ch = 0; ch < 4; ++ch) {
        const int m0 = ch * 96;
        __syncthreads();
        for (int i = t; i < 1920; i += 256) {   // merge the two partials
            const int row = i / 24, q = i % 24;
            const size_t off = (size_t)row * MFEAT + m0 + q * 4;
            const ushort4 ua = *(const ushort4*)(ktg0 + off);
            const ushort4 ub = *(const ushort4*)(ktg1 + off);
            const uint2 pk2 = pk4bf(bf2f(ua.x) + bf2f(ub.x), bf2f(ua.y) + bf2f(ub.y),
                                    bf2f(ua.z) + bf2f(ub.z), bf2f(ua.w) + bf2f(ub.w));
            *(uint2*)&KT[row][q * 4] = pk2;
        }
        __syncthreads();

        #pragma unroll
        for (int mt = 0; mt < 6; ++mt) {
            bf16x8 afw[2];
            #pragma unroll
            for (int ks = 0; ks < 2; ++ks)
                afw[ks] = *(const bf16x8*)(worf_ts +
                    (size_t)(h * MFEAT + m0 + mt * 16 + lr) * HDIM + ks * 32 + lg * 8);
            #pragma unroll
            for (int nt = 0; nt < 2; ++nt) {
                f32x4 p = {};
                p = __builtin_amdgcn_mfma_f32_16x16x32_bf16(afw[0], bq[nt][0], p, 0, 0, 0);
                p = __builtin_amdgcn_mfma_f32_16x16x32_bf16(afw[1], bq[nt][1], p, 0, 0, 0);
                const uint2 pk2 = pk4bf(__expf(p[0] - sqn[nt]), __expf(p[1] - sqn[nt]),
                                        __expf(p[2] - sqn[nt]), __expf(p[3] - sqn[nt]));
                *(uint2*)&P[w][nt * 16 + lr][mt * 16 + lg * 4] = pk2;
            }
        }
        asm volatile("s_waitcnt lgkmcnt(0)" ::: "memory");
        __builtin_amdgcn_sched_barrier(0);

        #pragma unroll
        for (int ks = 0; ks < 3; ++ks) {
            bf16x8 bp[2];
            #pragma unroll
            for (int nt = 0; nt < 2; ++nt)
                bp[nt] = *(const bf16x8*)&P[w][nt * 16 + lr][ks * 32 + lg * 8];
            #pragma unroll
            for (int ct = 0; ct < 5; ++ct) {
                const bf16x8 av = *(const bf16x8*)&KT[ct * 16 + lr][ks * 32 + lg * 8];
                #pragma unroll
                for (int nt = 0; nt < 2; ++nt)
                    acc[ct][nt] = __builtin_amdgcn_mfma_f32_16x16x32_bf16(av, bp[nt], acc[ct][nt], 0, 0, 0);
            }
        }
    }

    #pragma unroll
    for (int nt = 0; nt < 2; ++nt) {
        const float d = __shfl(acc[4][nt][0], lr);
        const float inv = 1.0f / (d + EPSP);
        const int token = b * SEQ + nw + nt * 16 + lr;
        #pragma unroll
        for (int ct = 0; ct < 4; ++ct) {
            const uint2 o2 = pk4bf(acc[ct][nt][0] * inv, acc[ct][nt][1] * inv,
                                   acc[ct][nt][2] * inv, acc[ct][nt][3] * inv);
            *(uint2*)&attn[(size_t)token * DIMD + h * 64 + ct * 16 + lg * 4] = o2;
        }
    }
}

// ---------------------------------------------------------------------------
extern "C" void kernel_launch(void* const* d_in, const int* in_sizes, int n_in,
                              void* d_out, int out_size, void* d_ws, size_t ws_size,
                              hipStream_t stream) {
    const float* x      = (const float*)d_in[0];
    const float* ln1_g  = (const float*)d_in[1];
    const float* ln1_b  = (const float*)d_in[2];
    const float* qkv_w  = (const float*)d_in[3];
    const float* qkv_b  = (const float*)d_in[4];
    const float* w_orf  = (const float*)d_in[5];
    const float* proj_w = (const float*)d_in[6];
    const float* proj_b = (const float*)d_in[7];
    const float* ln2_g  = (const float*)d_in[8];
    const float* ln2_b  = (const float*)d_in[9];
    const float* fc1_w  = (const float*)d_in[10];
    const float* fc1_b  = (const float*)d_in[11];
    const float* fc2_w  = (const float*)d_in[12];
    const float* fc2_b  = (const float*)d_in[13];
    float* out = (float*)d_out;

    // Workspace layout (bytes), total 265,814,016 B (= round-3 proven size).
    char* wsb = (char*)d_ws;
    unsigned short* qkvb    = (unsigned short*)wsb;                  // bf16 T*2304 [0, 150994944)
    unsigned short* attn    = (unsigned short*)(wsb + 150994944);    // bf16 T*768  [.., 201326592)
    unsigned short* ktvT    = (unsigned short*)(wsb + 201326592);    // bf16 2 x 384*80*384 = 47,185,920 -> ends 248,512,512
    unsigned short* worf_ts = (unsigned short*)(wsb + 248512512);    // bf16 12*384*64 = 589,824 -> ends 249,102,336
    unsigned char*  y2f8    = (unsigned char*)(wsb + 201326592);     // fp8 T*768 (ktvT parts dead)
    unsigned char*  hidf8   = (unsigned char*)wsb;                   // fp8 T*3072 (qkvb dead)
    unsigned short* qkv_wt  = (unsigned short*)(wsb + 251658240);    // bf16 [2304,768] 3,538,944
    unsigned short* proj_wt = (unsigned short*)(wsb + 255197184);    // bf16 [768,768]  1,179,648
    unsigned char*  fc1_wf8 = (unsigned char*)(wsb + 256376832);     // fp8 [3072,768]  2,359,296
    unsigned char*  fc2_wf8 = (unsigned char*)(wsb + 261095424);     // fp8 [768,3072]  2,359,296
    unsigned short* xln     = (unsigned short*)d_out;                // bf16 T*768 in d_out (free until step 5)

    // 0) weight prep
    wconv<<<dim3(2304 / 32, 768 / 32), 256, 0, stream>>>(qkv_w, qkv_wt, DIMD, 2304);
    wconv<<<dim3(768 / 32, 768 / 32), 256, 0, stream>>>(proj_w, proj_wt, DIMD, DIMD);
    wconv_f8<<<dim3(3072 / 32, 768 / 32), 256, 0, stream>>>(fc1_w, fc1_wf8, DIMD, HIDDEN);
    wconv_f8<<<dim3(768 / 32, 3072 / 32), 256, 0, stream>>>(fc2_w, fc2_wf8, HIDDEN, DIMD);
    wprep<<<dim3(MFEAT / 32, HDIM / 32, HEADS), 256, 0, stream>>>(w_orf, worf_ts);
    // 1) xln = LN1(x) (bf16, in d_out)
    ln_vec<1><<<NTOK, 256, 0, stream>>>(x, ln1_g, ln1_b, xln);
    // 2) qkv = xln @ qkv_w + qkv_b (bf16, BK=64)
    gemm_bk64<0, false, true><<<dim3(2304 / 128, NTOK / 128), 256, 0, stream>>>(
        xln, qkv_wt, qkv_b, nullptr, qkvb, DIMD, 2304);
    // 3) phase A: two partial ktvT halves (768 blocks -> 3/CU balanced)
    ktv_mfma<<<dim3(HEADS, BATCH, 2), 256, 0, stream>>>(qkvb, worf_ts, ktvT);
    // 4) phase B: attn out (bf16), merges partials during staging
    attn_out_mfma<<<dim3(SEQ / 128, HEADS, BATCH), 256, 0, stream>>>(
        qkvb, worf_ts, ktvT, attn);
    // 5) h = x + attn @ proj_w + proj_b -> d_out (f32, BK=32 3-buf)
    gemm_bk32<0, true, false><<<dim3(DIMD / 128, NTOK / 128), 256, 0, stream>>>(
        attn, proj_wt, proj_b, x, out, DIMD, DIMD);
    // 6) y2f8 = LN2(h) (fp8 kp128; ktvT/worf_ts dead)
    ln_vec<2><<<NTOK, 256, 0, stream>>>(out, ln2_g, ln2_b, y2f8);
    // 7) hidf8 = gelu(y2f8 @ fc1_w + fc1_b) (MX GEMM, fp8 kp128 out)
    gemm_mx<1, false, 2><<<dim3(HIDDEN / 128, NTOK / 128), 256, 0, stream>>>(
        y2f8, fc1_wf8, fc1_b, nullptr, hidf8, DIMD, HIDDEN);
    // 8) out = h + hidf8 @ fc2_w + fc2_b (MX GEMM, in-place residual)
    gemm_mx<0, true, 0><<<dim3(DIMD / 128, NTOK / 128), 256, 0, stream>>>(
        hidf8, fc2_wf8, fc2_b, out, out, HIDDEN, DIMD);
}

// Round 20
// 737.479 us; speedup vs baseline: 1.0168x; 1.0168x over previous
//
#include <hip/hip_runtime.h>
#include <hip/hip_bf16.h>

// Problem constants
#define NTOK   32768          // 32 * 1024 tokens
#define BATCH  32
#define SEQ    1024
#define DIMD   768
#define HEADS  12
#define HDIM   64
#define MFEAT  384
#define HIDDEN 3072
#define SCALE  0.35355339059327379f   // 64^-0.25
#define HALF_SCALE2 0.0625f           // 0.5 * SCALE^2
#define EPSP   3.84e-6f               // 1e-8 / RSM^2 (RSM factors cancel in out)
#define WSCL   64.0f                  // fp8 weight pre-scale (absorbed by MX B-scale 2^-6)
#define SCA_ONE   0x7F7F7F7Fu         // e8m0 1.0
#define SCB_I64   0x79797979u         // e8m0 2^-6 = 1/64

typedef __attribute__((ext_vector_type(8))) short bf16x8;
typedef __attribute__((ext_vector_type(4))) float f32x4;
typedef __attribute__((ext_vector_type(2))) long long llong2;
typedef __attribute__((ext_vector_type(8))) int i32x8;

static __device__ __forceinline__ float bf2f(unsigned short u) {
    return __uint_as_float(((unsigned)u) << 16);
}
static __device__ __forceinline__ unsigned short f2bf(float f) {
    unsigned u = __float_as_uint(f);
    return (unsigned short)((u + 0x7FFFu + ((u >> 16) & 1u)) >> 16);  // RNE
}
// pack 4 f32 -> 4 bf16 (8B) via v_cvt_pk_bf16_f32 (compiler-generated, RNE)
static __device__ __forceinline__ uint2 pk4bf(float e0, float e1, float e2, float e3) {
    const __hip_bfloat162 lo = __float22bfloat162_rn(make_float2(e0, e1));
    const __hip_bfloat162 hi = __float22bfloat162_rn(make_float2(e2, e3));
    uint2 r;
    r.x = *(const unsigned*)&lo;
    r.y = *(const unsigned*)&hi;
    return r;
}
// f32 -> OCP e4m3fn, RNE, saturate (software path; off critical path)
static __device__ __forceinline__ unsigned char f2e4m3(float f) {
    unsigned u = __float_as_uint(f);
    const unsigned char s = (unsigned char)((u >> 24) & 0x80);
    const float af = __uint_as_float(u & 0x7FFFFFFF);
    if (!(af < 464.0f)) return s | 0x7E;                 // saturate (448)
    int e = (int)((u >> 23) & 0xFF) - 127;
    if (e < -6) e = -6;
    const float ulp = __uint_as_float((unsigned)((e - 3 + 127) << 23));  // 2^(e-3)
    const float q = rintf(af / ulp) * ulp;               // RNE quantize
    if (q == 0.0f) return s;
    const unsigned v = __float_as_uint(q);
    const int qe = (int)((v >> 23) & 0xFF) - 127;
    if (qe < -6) return s | (unsigned char)(q * 512.0f); // subnormal m*2^-9
    return s | (unsigned char)(((qe + 7) << 3) | ((v >> 20) & 7));
}
// hardware f32 -> fp8 e4m3 (gfx950 OCP), 1 VALU op
static __device__ __forceinline__ unsigned char f2e4m3_hw(float v) {
    unsigned r = 0;
    asm("v_cvt_pk_fp8_f32 %0, %1, %1" : "+v"(r) : "v"(v));
    return (unsigned char)(r & 0xFF);
}
// MX byte permutation within each 128-k group (fp8 path)
static __device__ __forceinline__ int kp128(int kl) {   // kl in [0,128)
    return (((kl >> 4) & 1) << 6) + ((kl >> 5) << 4) + (kl & 15);
}
// gelu tanh-approx, exp form with hw rcp
static __device__ __forceinline__ float gelu_fast(float v) {
    const float c = 0.7978845608028654f;
    const float u = c * v * (1.0f + 0.044715f * v * v);
    return v * __builtin_amdgcn_rcpf(1.0f + __expf(-2.0f * u));
}
static __device__ __forceinline__ void gload16(const void* g, void* l) {
    __builtin_amdgcn_global_load_lds(
        (const __attribute__((address_space(1))) void*)g,
        (__attribute__((address_space(3))) void*)l, 16, 0, 0);
}

// ---------------- vectorized LayerNorm; OT: 1 = bf16 out, 2 = fp8 out (kp128)
template <int OT>
__global__ __launch_bounds__(256) void ln_vec(
    const float* __restrict__ x, const float* __restrict__ g,
    const float* __restrict__ bta, void* __restrict__ o) {
    const size_t row = blockIdx.x;
    const float* xr = x + row * DIMD;
    const int t = threadIdx.x;
    float4 v = make_float4(0.f, 0.f, 0.f, 0.f);
    if (t < 192) v = *(const float4*)(xr + t * 4);
    float s  = v.x + v.y + v.z + v.w;
    float sq = v.x * v.x + v.y * v.y + v.z * v.z + v.w * v.w;
    const int lane = t & 63, w = t >> 6;
    #pragma unroll
    for (int off = 32; off > 0; off >>= 1) {
        s  += __shfl_down(s, off, 64);
        sq += __shfl_down(sq, off, 64);
    }
    __shared__ float red[2][4];
    if (lane == 0) { red[0][w] = s; red[1][w] = sq; }
    __syncthreads();
    s  = red[0][0] + red[0][1] + red[0][2] + red[0][3];
    sq = red[1][0] + red[1][1] + red[1][2] + red[1][3];
    const float mu  = s * (1.0f / DIMD);
    const float var = sq * (1.0f / DIMD) - mu * mu;
    const float r = rsqrtf(var + 1e-5f);
    if (t < 192) {
        const float4 gv = *(const float4*)(g + t * 4);
        const float4 bv = *(const float4*)(bta + t * 4);
        const float o0 = (v.x - mu) * r * gv.x + bv.x;
        const float o1 = (v.y - mu) * r * gv.y + bv.y;
        const float o2 = (v.z - mu) * r * gv.z + bv.z;
        const float o3 = (v.w - mu) * r * gv.w + bv.w;
        if constexpr (OT == 1) {
            unsigned short* orow = (unsigned short*)o + row * DIMD + t * 4;
            *(ushort4*)orow = make_ushort4(f2bf(o0), f2bf(o1), f2bf(o2), f2bf(o3));
        } else {
            const int k = t * 4;
            const int gb = k & ~127, kl = k & 127;
            unsigned char* orow = (unsigned char*)o + row * DIMD + gb + kp128(kl);
            uchar4 p; p.x = f2e4m3(o0); p.y = f2e4m3(o1);
            p.z = f2e4m3(o2); p.w = f2e4m3(o3);
            *(uchar4*)orow = p;
        }
    }
}

// ---------------- weight convert + transpose: W[K,N] f32 -> Wt[N,K] bf16 ---
__global__ __launch_bounds__(256) void wconv(
    const float* __restrict__ W, unsigned short* __restrict__ Wt, int K, int N) {
    __shared__ float tile[32][33];
    const int n0 = blockIdx.x << 5, k0 = blockIdx.y << 5;
    const int tn = threadIdx.x & 31, tg = threadIdx.x >> 5;
    #pragma unroll
    for (int i = 0; i < 4; ++i) {
        const int k = (tg << 2) + i;
        tile[k][tn] = W[(size_t)(k0 + k) * N + n0 + tn];
    }
    __syncthreads();
    #pragma unroll
    for (int i = 0; i < 4; ++i) {
        const int n = (tg << 2) + i;
        Wt[(size_t)(n0 + n) * K + k0 + tn] = f2bf(tile[tn][n]);
    }
}

// ---------------- weight convert: W[K,N] f32 -> Wt[N,K] fp8 (x64, kp128) ---
__global__ __launch_bounds__(256) void wconv_f8(
    const float* __restrict__ W, unsigned char* __restrict__ Wt, int K, int N) {
    __shared__ float tile[32][33];
    const int n0 = blockIdx.x << 5, k0 = blockIdx.y << 5;
    const int tn = threadIdx.x & 31, tg = threadIdx.x >> 5;
    #pragma unroll
    for (int i = 0; i < 4; ++i) {
        const int k = (tg << 2) + i;
        tile[k][tn] = W[(size_t)(k0 + k) * N + n0 + tn];
    }
    __syncthreads();
    #pragma unroll
    for (int i = 0; i < 4; ++i) {
        const int n = (tg << 2) + i;
        const int k = k0 + tn;
        const int gb = k & ~127, kl = k & 127;
        Wt[(size_t)(n0 + n) * K + gb + kp128(kl)] = f2e4m3(WSCL * tile[tn][n]);
    }
}

// ---------------- worf prep: worf_ts[h][m][c] = bf16(SCALE * worf[h][c][m])
__global__ __launch_bounds__(256) void wprep(
    const float* __restrict__ worf, unsigned short* __restrict__ worf_ts) {
    __shared__ float tile[32][33];
    const int m0 = blockIdx.x << 5, c0 = blockIdx.y << 5, h = blockIdx.z;
    const int tn = threadIdx.x & 31, tg = threadIdx.x >> 5;
    #pragma unroll
    for (int i = 0; i < 4; ++i) {
        const int c = (tg << 2) + i;
        tile[c][tn] = worf[(size_t)(h * HDIM + c0 + c) * MFEAT + m0 + tn];
    }
    __syncthreads();
    #pragma unroll
    for (int i = 0; i < 4; ++i) {
        const int m = (tg << 2) + i;
        worf_ts[(size_t)(h * MFEAT + m0 + m) * HDIM + c0 + tn] =
            f2bf(SCALE * tile[tn][m]);
    }
}

// ---------------- bf16 GEMM BK=64 S0/S1 (round-17 measured best for qkv) ---
template <int ACT, bool RES, bool OBF16>
__global__ __launch_bounds__(256, 2) void gemm_bk64(
    const unsigned short* __restrict__ A, const unsigned short* __restrict__ Wt,
    const float* __restrict__ bias, const float* __restrict__ resid,
    void* __restrict__ Craw, int K, int N) {
    __shared__ unsigned short As0[2][4096], As1[2][4096];   // 16 KB
    __shared__ unsigned short Bs0[2][4096], Bs1[2][4096];   // 16 KB
    const int t = threadIdx.x;
    const int w = t >> 6, l = t & 63;
    const int ncol = gridDim.x;
    const int lin = blockIdx.y * ncol + blockIdx.x;
    const int cpx = (ncol * gridDim.y) >> 3;
    const int wg = (lin & 7) * cpx + (lin >> 3);
    const int row0 = (wg / ncol) << 7, col0 = (wg % ncol) << 7;
    const int wr = (w >> 1) << 6, wc = (w & 1) << 6;

    const int sc = (((l & 3) ^ ((l >> 3) & 3)) << 3);   // bf16 units in 64B seg
    const size_t arow0 = (size_t)(row0 + w * 32 + (l >> 2)) * K;
    const size_t arow1 = arow0 + (size_t)16 * K;
    const size_t brow0 = (size_t)(col0 + w * 32 + (l >> 2)) * K;
    const size_t brow1 = brow0 + (size_t)16 * K;

    f32x4 acc[4][4] = {};
    const int NT = K >> 6;

    auto stage = [&](int bi, int s) {
        const size_t ko = (size_t)s << 6;   // 64 bf16 per K-step
        gload16(A + arow0 + ko + sc,      &As0[bi][w * 1024]);
        gload16(A + arow1 + ko + sc,      &As0[bi][w * 1024 + 512]);
        gload16(A + arow0 + ko + 32 + sc, &As1[bi][w * 1024]);
        gload16(A + arow1 + ko + 32 + sc, &As1[bi][w * 1024 + 512]);
        gload16(Wt + brow0 + ko + sc,      &Bs0[bi][w * 1024]);
        gload16(Wt + brow1 + ko + sc,      &Bs0[bi][w * 1024 + 512]);
        gload16(Wt + brow0 + ko + 32 + sc, &Bs1[bi][w * 1024]);
        gload16(Wt + brow1 + ko + 32 + sc, &Bs1[bi][w * 1024 + 512]);
    };

    stage(0, 0);
    const int lr = l & 15, lg = l >> 4;
    const int xoff = ((lg ^ ((lr >> 1) & 3)) << 3);
    for (int s = 0; s < NT; ++s) {
        asm volatile("s_waitcnt vmcnt(0)" ::: "memory");
        __builtin_amdgcn_s_barrier();
        __builtin_amdgcn_sched_barrier(0);
        if (s + 1 < NT) stage((s + 1) & 1, s + 1);
        const unsigned short* a0 = &As0[s & 1][0];
        const unsigned short* a1 = &As1[s & 1][0];
        const unsigned short* b0 = &Bs0[s & 1][0];
        const unsigned short* b1 = &Bs1[s & 1][0];
        bf16x8 af[4][2], bfr[4][2];
        #pragma unroll
        for (int f = 0; f < 4; ++f) {
            const int ra = ((wr + f * 16 + lr) << 5) + xoff;
            const int rb = ((wc + f * 16 + lr) << 5) + xoff;
            af[f][0]  = *(const bf16x8*)(a0 + ra);
            af[f][1]  = *(const bf16x8*)(a1 + ra);
            bfr[f][0] = *(const bf16x8*)(b0 + rb);
            bfr[f][1] = *(const bf16x8*)(b1 + rb);
        }
        #pragma unroll
        for (int ks = 0; ks < 2; ++ks)
            #pragma unroll
            for (int fi = 0; fi < 4; ++fi)
                #pragma unroll
                for (int fj = 0; fj < 4; ++fj)
                    acc[fi][fj] = __builtin_amdgcn_mfma_f32_16x16x32_bf16(
                        af[fi][ks], bfr[fj][ks], acc[fi][fj], 0, 0, 0);
    }

    float bv[4];
    #pragma unroll
    for (int fj = 0; fj < 4; ++fj) bv[fj] = bias[col0 + wc + fj * 16 + lr];
    #pragma unroll
    for (int fi = 0; fi < 4; ++fi) {
        #pragma unroll
        for (int r = 0; r < 4; ++r) {
            const int row = row0 + wr + fi * 16 + lg * 4 + r;
            const size_t base = (size_t)row * N + col0 + wc + lr;
            #pragma unroll
            for (int fj = 0; fj < 4; ++fj) {
                float v = acc[fi][fj][r] + bv[fj];
                if constexpr (RES) v += resid[base + fj * 16];
                if constexpr (ACT == 1) v = gelu_fast(v);
                if constexpr (OBF16) ((unsigned short*)Craw)[base + fj * 16] = f2bf(v);
                else                 ((float*)Craw)[base + fj * 16] = v;
            }
        }
    }
}

// ---------------- bf16 GEMM BK=32 3-buf (round-16 proven, for proj) --------
template <int ACT, bool RES, bool OBF16>
__global__ __launch_bounds__(256, 2) void gemm_bk32(
    const unsigned short* __restrict__ A, const unsigned short* __restrict__ Wt,
    const float* __restrict__ bias, const float* __restrict__ resid,
    void* __restrict__ Craw, int K, int N) {
    __shared__ unsigned short As[3][128 * 32];
    __shared__ unsigned short Bs[3][128 * 32];
    const int t = threadIdx.x;
    const int w = t >> 6, l = t & 63;
    const int ncol = gridDim.x;
    const int lin = blockIdx.y * ncol + blockIdx.x;
    const int cpx = (ncol * gridDim.y) >> 3;
    const int wg = (lin & 7) * cpx + (lin >> 3);
    const int row0 = (wg / ncol) << 7, col0 = (wg % ncol) << 7;
    const int wr = (w >> 1) << 6, wc = (w & 1) << 6;

    const int sc = (((l & 3) ^ ((l >> 3) & 3)) << 3);
    const unsigned short* ag0 = A  + (size_t)(row0 + w * 32 + (l >> 2)) * K + sc;
    const unsigned short* ag1 = ag0 + (size_t)16 * K;
    const unsigned short* bg0 = Wt + (size_t)(col0 + w * 32 + (l >> 2)) * K + sc;
    const unsigned short* bg1 = bg0 + (size_t)16 * K;

    f32x4 acc[4][4] = {};
    const int NT = K >> 5;

    auto stage = [&](int bi, int s) {
        const size_t ko = (size_t)s << 5;
        gload16(ag0 + ko, &As[bi][w * 1024]);
        gload16(ag1 + ko, &As[bi][w * 1024 + 512]);
        gload16(bg0 + ko, &Bs[bi][w * 1024]);
        gload16(bg1 + ko, &Bs[bi][w * 1024 + 512]);
    };

    stage(0, 0);
    stage(1, 1);
    const int lr = l & 15, lg = l >> 4;
    const int lkx = (lg << 3) ^ ((((lr >> 1) & 3)) << 3);
    int cur = 0;
    for (int s = 0; s < NT; ++s) {
        if (s + 1 < NT) asm volatile("s_waitcnt vmcnt(4)" ::: "memory");
        else            asm volatile("s_waitcnt vmcnt(0)" ::: "memory");
        __builtin_amdgcn_s_barrier();
        __builtin_amdgcn_sched_barrier(0);
        if (s + 2 < NT) {
            int sb = cur + 2; if (sb >= 3) sb -= 3;
            stage(sb, s + 2);
        }
        const unsigned short* ab = &As[cur][0];
        const unsigned short* bb = &Bs[cur][0];
        bf16x8 af[4], bfr[4];
        #pragma unroll
        for (int f = 0; f < 4; ++f) {
            af[f]  = *(const bf16x8*)(ab + (wr + f * 16 + lr) * 32 + lkx);
            bfr[f] = *(const bf16x8*)(bb + (wc + f * 16 + lr) * 32 + lkx);
        }
        #pragma unroll
        for (int fi = 0; fi < 4; ++fi)
            #pragma unroll
            for (int fj = 0; fj < 4; ++fj)
                acc[fi][fj] = __builtin_amdgcn_mfma_f32_16x16x32_bf16(
                    af[fi], bfr[fj], acc[fi][fj], 0, 0, 0);
        cur = (cur + 1 == 3) ? 0 : cur + 1;
    }

    float bv[4];
    #pragma unroll
    for (int fj = 0; fj < 4; ++fj) bv[fj] = bias[col0 + wc + fj * 16 + lr];
    #pragma unroll
    for (int fi = 0; fi < 4; ++fi) {
        #pragma unroll
        for (int r = 0; r < 4; ++r) {
            const int row = row0 + wr + fi * 16 + lg * 4 + r;
            const size_t base = (size_t)row * N + col0 + wc + lr;
            #pragma unroll
            for (int fj = 0; fj < 4; ++fj) {
                float v = acc[fi][fj][r] + bv[fj];
                if constexpr (RES) v += resid[base + fj * 16];
                if constexpr (ACT == 1) v = gelu_fast(v);
                if constexpr (OBF16) ((unsigned short*)Craw)[base + fj * 16] = f2bf(v);
                else                 ((float*)Craw)[base + fj * 16] = v;
            }
        }
    }
}

// ---------------- MX-fp8 MFMA GEMM (round-16 proven): fc1 + fc2 ------------
template <int ACT, bool RES, int OT>
__global__ __launch_bounds__(256, 2) void gemm_mx(
    const unsigned char* __restrict__ A, const unsigned char* __restrict__ Wt,
    const float* __restrict__ bias, const float* __restrict__ resid,
    void* __restrict__ Craw, int K, int N) {
    __shared__ unsigned char As0[2][8192], As1[2][8192];   // 32 KB
    __shared__ unsigned char Bs0[2][8192], Bs1[2][8192];   // 32 KB
    const int t = threadIdx.x;
    const int w = t >> 6, l = t & 63;
    const int ncol = gridDim.x;
    const int lin = blockIdx.y * ncol + blockIdx.x;
    const int cpx = (ncol * gridDim.y) >> 3;
    const int wg = (lin & 7) * cpx + (lin >> 3);
    const int row0 = (wg / ncol) << 7, col0 = (wg % ncol) << 7;
    const int wr = (w >> 1) << 6, wc = (w & 1) << 6;

    const int sc = (((l & 3) ^ ((l >> 3) & 3)) << 4);
    const size_t arow0 = (size_t)(row0 + w * 32 + (l >> 2)) * K;
    const size_t arow1 = arow0 + (size_t)16 * K;
    const size_t brow0 = (size_t)(col0 + w * 32 + (l >> 2)) * K;
    const size_t brow1 = brow0 + (size_t)16 * K;

    f32x4 acc[4][4] = {};
    const int NT = K >> 7;

    auto stage = [&](int bi, int s) {
        const size_t ko = (size_t)s << 7;
        gload16(A + arow0 + ko + sc,      &As0[bi][w * 2048]);
        gload16(A + arow1 + ko + sc,      &As0[bi][w * 2048 + 1024]);
        gload16(A + arow0 + ko + 64 + sc, &As1[bi][w * 2048]);
        gload16(A + arow1 + ko + 64 + sc, &As1[bi][w * 2048 + 1024]);
        gload16(Wt + brow0 + ko + sc,      &Bs0[bi][w * 2048]);
        gload16(Wt + brow1 + ko + sc,      &Bs0[bi][w * 2048 + 1024]);
        gload16(Wt + brow0 + ko + 64 + sc, &Bs1[bi][w * 2048]);
        gload16(Wt + brow1 + ko + 64 + sc, &Bs1[bi][w * 2048 + 1024]);
    };

    stage(0, 0);
    const int lr = l & 15, lg = l >> 4;
    const int xoff = ((lg ^ ((lr >> 1) & 3)) << 4);
    for (int s = 0; s < NT; ++s) {
        asm volatile("s_waitcnt vmcnt(0)" ::: "memory");
        __builtin_amdgcn_s_barrier();
        __builtin_amdgcn_sched_barrier(0);
        if (s + 1 < NT) stage((s + 1) & 1, s + 1);
        const unsigned char* a0 = &As0[s & 1][0];
        const unsigned char* a1 = &As1[s & 1][0];
        const unsigned char* b0 = &Bs0[s & 1][0];
        const unsigned char* b1 = &Bs1[s & 1][0];
        i32x8 afm[4], bfm[4];
        #pragma unroll
        for (int f = 0; f < 4; ++f) {
            const int ra = ((wr + f * 16 + lr) << 6) + xoff;
            const int rb = ((wc + f * 16 + lr) << 6) + xoff;
            ((llong2*)&afm[f])[0] = *(const llong2*)(a0 + ra);
            ((llong2*)&afm[f])[1] = *(const llong2*)(a1 + ra);
            ((llong2*)&bfm[f])[0] = *(const llong2*)(b0 + rb);
            ((llong2*)&bfm[f])[1] = *(const llong2*)(b1 + rb);
        }
        #pragma unroll
        for (int fi = 0; fi < 4; ++fi)
            #pragma unroll
            for (int fj = 0; fj < 4; ++fj)
                acc[fi][fj] = __builtin_amdgcn_mfma_scale_f32_16x16x128_f8f6f4(
                    afm[fi], bfm[fj], acc[fi][fj], 0, 0,
                    0, SCA_ONE, 0, SCB_I64);
    }

    float bv[4];
    #pragma unroll
    for (int fj = 0; fj < 4; ++fj) bv[fj] = bias[col0 + wc + fj * 16 + lr];
    #pragma unroll
    for (int fi = 0; fi < 4; ++fi) {
        #pragma unroll
        for (int r = 0; r < 4; ++r) {
            const int row = row0 + wr + fi * 16 + lg * 4 + r;
            const size_t base = (size_t)row * N + col0 + wc + lr;
            #pragma unroll
            for (int fj = 0; fj < 4; ++fj) {
                float v = acc[fi][fj][r] + bv[fj];
                if constexpr (RES) v += resid[base + fj * 16];
                if constexpr (ACT == 1) v = gelu_fast(v);
                if constexpr (OT == 2) {
                    const int cl = wc + fj * 16 + lr;
                    ((unsigned char*)Craw)[(size_t)row * N + col0 + kp128(cl)] =
                        f2e4m3_hw(v);
                } else {
                    ((float*)Craw)[base + fj * 16] = v;
                }
            }
        }
    }
}

// ---------------- Phase A (MFMA): per (b,h): ktvT[c][m] (+ksum row 64) -----
__global__ __launch_bounds__(256, 1) void ktv_mfma(
    const unsigned short* __restrict__ qkvb,
    const unsigned short* __restrict__ worf_ts,
    unsigned short* __restrict__ ktvT) {
    const int h = blockIdx.x, b = blockIdx.y, bh = b * HEADS + h;
    __shared__ __align__(16) unsigned short Klds[32][72];
    __shared__ __align__(16) unsigned short VT[80][40];
    __shared__ __align__(16) unsigned short P[4][96][40];
    const int t = threadIdx.x, w = t >> 6, l = t & 63;
    const int lr = l & 15, lg = l >> 4;
    const int m0 = w * 96;

    bf16x8 bfw[6][2];
    #pragma unroll
    for (int mt = 0; mt < 6; ++mt)
        #pragma unroll
        for (int ks = 0; ks < 2; ++ks)
            bfw[mt][ks] = *(const bf16x8*)(worf_ts +
                (size_t)(h * MFEAT + m0 + mt * 16 + lr) * HDIM + ks * 32 + lg * 8);

    f32x4 acc[5][6] = {};

    for (int i = t; i < 16 * 40; i += 256) {
        const int r = 64 + i / 40, cc = i % 40;
        VT[r][cc] = (r == 64) ? (unsigned short)0x3F80 : (unsigned short)0;
    }
    const unsigned short* kglob = qkvb + (size_t)b * SEQ * 2304 + 768 + h * 64;
    const unsigned short* vglob = kglob + 768;

    for (int n0 = 0; n0 < SEQ; n0 += 32) {
        __syncthreads();
        {
            const int row = t >> 3, c8 = (t & 7) << 3;
            *(bf16x8*)&Klds[row][c8] =
                *(const bf16x8*)(kglob + (size_t)(n0 + row) * 2304 + c8);
        }
        {
            const int n = t & 31, c0 = (t >> 5) << 3;
            const unsigned short* src = vglob + (size_t)(n0 + n) * 2304 + c0;
            ushort4 v0 = *(const ushort4*)src;
            ushort4 v1 = *(const ushort4*)(src + 4);
            VT[c0 + 0][n] = v0.x; VT[c0 + 1][n] = v0.y;
            VT[c0 + 2][n] = v0.z; VT[c0 + 3][n] = v0.w;
            VT[c0 + 4][n] = v1.x; VT[c0 + 5][n] = v1.y;
            VT[c0 + 6][n] = v1.z; VT[c0 + 7][n] = v1.w;
        }
        __syncthreads();

        bf16x8 afk[2][2];
        float sqv[2][4];
        #pragma unroll
        for (int ns = 0; ns < 2; ++ns) {
            float s = 0.f;
            #pragma unroll
            for (int ks = 0; ks < 2; ++ks) {
                afk[ns][ks] = *(const bf16x8*)&Klds[ns * 16 + lr][ks * 32 + lg * 8];
                #pragma unroll
                for (int j = 0; j < 8; ++j) {
                    const float f = bf2f((unsigned short)afk[ns][ks][j]);
                    s += f * f;
                }
            }
            s += __shfl_xor(s, 16);
            s += __shfl_xor(s, 32);
            s *= HALF_SCALE2;
            #pragma unroll
            for (int r = 0; r < 4; ++r)
                sqv[ns][r] = __shfl(s, (lg << 2) + r);
        }

        #pragma unroll
        for (int mt = 0; mt < 6; ++mt) {
            #pragma unroll
            for (int ns = 0; ns < 2; ++ns) {
                f32x4 p = {};
                p = __builtin_amdgcn_mfma_f32_16x16x32_bf16(afk[ns][0], bfw[mt][0], p, 0, 0, 0);
                p = __builtin_amdgcn_mfma_f32_16x16x32_bf16(afk[ns][1], bfw[mt][1], p, 0, 0, 0);
                const uint2 pk2 = pk4bf(__expf(p[0] - sqv[ns][0]), __expf(p[1] - sqv[ns][1]),
                                        __expf(p[2] - sqv[ns][2]), __expf(p[3] - sqv[ns][3]));
                *(uint2*)&P[w][mt * 16 + lr][ns * 16 + lg * 4] = pk2;
            }
        }
        asm volatile("s_waitcnt lgkmcnt(0)" ::: "memory");
        __builtin_amdgcn_sched_barrier(0);

        bf16x8 afv[5];
        #pragma unroll
        for (int ct = 0; ct < 5; ++ct)
            afv[ct] = *(const bf16x8*)&VT[ct * 16 + lr][lg * 8];
        #pragma unroll
        for (int mt = 0; mt < 6; ++mt) {
            const bf16x8 bp = *(const bf16x8*)&P[w][mt * 16 + lr][lg * 8];
            #pragma unroll
            for (int ct = 0; ct < 5; ++ct)
                acc[ct][mt] = __builtin_amdgcn_mfma_f32_16x16x32_bf16(afv[ct], bp, acc[ct][mt], 0, 0, 0);
        }
    }

    unsigned short* dst = ktvT + (size_t)bh * 80 * MFEAT;
    #pragma unroll
    for (int ct = 0; ct < 5; ++ct)
        #pragma unroll
        for (int mt = 0; mt < 6; ++mt)
            #pragma unroll
            for (int r = 0; r < 4; ++r) {
                const int cc = ct * 16 + lg * 4 + r;
                const int m = m0 + mt * 16 + lr;
                dst[(size_t)cc * MFEAT + m] = f2bf(acc[ct][mt][r]);
            }
}

// ---------------- Phase B (MFMA): out^T[c,n] = sum_m ktvT[c,m] * phi_q[n,m]
__global__ __launch_bounds__(256) void attn_out_mfma(
    const unsigned short* __restrict__ qkvb,
    const unsigned short* __restrict__ worf_ts,
    const unsigned short* __restrict__ ktvT,
    unsigned short* __restrict__ attn) {
    const int n0 = blockIdx.x << 7;
    const int h = blockIdx.y, b = blockIdx.z, bh = b * HEADS + h;
    __shared__ __align__(16) unsigned short KT[80][104];
    __shared__ __align__(16) unsigned short P[4][32][104];
    const int t = threadIdx.x, w = t >> 6, l = t & 63;
    const int lr = l & 15, lg = l >> 4;
    const int nw = n0 + w * 32;

    bf16x8 bq[2][2];
    float sqn[2];
    #pragma unroll
    for (int nt = 0; nt < 2; ++nt) {
        float s = 0.f;
        #pragma unroll
        for (int ks = 0; ks < 2; ++ks) {
            bq[nt][ks] = *(const bf16x8*)(qkvb +
                (size_t)(b * SEQ + nw + nt * 16 + lr) * 2304 + h * 64 + ks * 32 + lg * 8);
            #pragma unroll
            for (int j = 0; j < 8; ++j) {
                const float f = bf2f((unsigned short)bq[nt][ks][j]);
                s += f * f;
            }
        }
        s += __shfl_xor(s, 16);
        s += __shfl_xor(s, 32);
        sqn[nt] = s * HALF_SCALE2;
    }

    f32x4 acc[5][2] = {};
    const unsigned short* ktg = ktvT + (size_t)bh * 80 * MFEAT;

    for (int ch = 0; ch < 4; ++ch) {
        const int m0 = ch * 96;
        __syncthreads();
        for (int i = t; i < 1920; i += 256) {
            const int row = i / 24, q = i % 24;
            *(ushort4*)&KT[row][q * 4] =
                *(const ushort4*)(ktg + (size_t)row * MFEAT + m0 + q * 4);
        }
        __syncthreads();

        #pragma unroll
        for (int mt = 0; mt < 6; ++mt) {
            bf16x8 afw[2];
            #pragma unroll
            for (int ks = 0; ks < 2; ++ks)
                afw[ks] = *(const bf16x8*)(worf_ts +
                    (size_t)(h * MFEAT + m0 + mt * 16 + lr) * HDIM + ks * 32 + lg * 8);
            #pragma unroll
            for (int nt = 0; nt < 2; ++nt) {
                f32x4 p = {};
                p = __builtin_amdgcn_mfma_f32_16x16x32_bf16(afw[0], bq[nt][0], p, 0, 0, 0);
                p = __builtin_amdgcn_mfma_f32_16x16x32_bf16(afw[1], bq[nt][1], p, 0, 0, 0);
                const uint2 pk2 = pk4bf(__expf(p[0] - sqn[nt]), __expf(p[1] - sqn[nt]),
                                        __expf(p[2] - sqn[nt]), __expf(p[3] - sqn[nt]));
                *(uint2*)&P[w][nt * 16 + lr][mt * 16 + lg * 4] = pk2;
            }
        }
        asm volatile("s_waitcnt lgkmcnt(0)" ::: "memory");
        __builtin_amdgcn_sched_barrier(0);

        #pragma unroll
        for (int ks = 0; ks < 3; ++ks) {
            bf16x8 bp[2];
            #pragma unroll
            for (int nt = 0; nt < 2; ++nt)
                bp[nt] = *(const bf16x8*)&P[w][nt * 16 + lr][ks * 32 + lg * 8];
            #pragma unroll
            for (int ct = 0; ct < 5; ++ct) {
                const bf16x8 av = *(const bf16x8*)&KT[ct * 16 + lr][ks * 32 + lg * 8];
                #pragma unroll
                for (int nt = 0; nt < 2; ++nt)
                    acc[ct][nt] = __builtin_amdgcn_mfma_f32_16x16x32_bf16(av, bp[nt], acc[ct][nt], 0, 0, 0);
            }
        }
    }

    #pragma unroll
    for (int nt = 0; nt < 2; ++nt) {
        const float d = __shfl(acc[4][nt][0], lr);
        const float inv = 1.0f / (d + EPSP);
        const int token = b * SEQ + nw + nt * 16 + lr;
        #pragma unroll
        for (int ct = 0; ct < 4; ++ct) {
            const uint2 o2 = pk4bf(acc[ct][nt][0] * inv, acc[ct][nt][1] * inv,
                                   acc[ct][nt][2] * inv, acc[ct][nt][3] * inv);
            *(uint2*)&attn[(size_t)token * DIMD + h * 64 + ct * 16 + lg * 4] = o2;
        }
    }
}

// ---------------------------------------------------------------------------
extern "C" void kernel_launch(void* const* d_in, const int* in_sizes, int n_in,
                              void* d_out, int out_size, void* d_ws, size_t ws_size,
                              hipStream_t stream) {
    const float* x      = (const float*)d_in[0];
    const float* ln1_g  = (const float*)d_in[1];
    const float* ln1_b  = (const float*)d_in[2];
    const float* qkv_w  = (const float*)d_in[3];
    const float* qkv_b  = (const float*)d_in[4];
    const float* w_orf  = (const float*)d_in[5];
    const float* proj_w = (const float*)d_in[6];
    const float* proj_b = (const float*)d_in[7];
    const float* ln2_g  = (const float*)d_in[8];
    const float* ln2_b  = (const float*)d_in[9];
    const float* fc1_w  = (const float*)d_in[10];
    const float* fc1_b  = (const float*)d_in[11];
    const float* fc2_w  = (const float*)d_in[12];
    const float* fc2_b  = (const float*)d_in[13];
    float* out = (float*)d_out;

    // Workspace layout (bytes), total 265,814,016 B (= round-3 proven size).
    char* wsb = (char*)d_ws;
    unsigned short* qkvb    = (unsigned short*)wsb;                  // bf16 T*2304 [0, 150994944)
    unsigned short* attn    = (unsigned short*)(wsb + 150994944);    // bf16 T*768  [.., 201326592)
    unsigned short* ktvT    = (unsigned short*)(wsb + 201326592);    // bf16 384*80*384 = 23,592,960
    unsigned short* worf_ts = (unsigned short*)(wsb + 224919552);    // bf16 12*384*64 = 589,824
    unsigned char*  y2f8    = (unsigned char*)(wsb + 201326592);     // fp8 T*768 (ktvT dead)
    unsigned char*  hidf8   = (unsigned char*)wsb;                   // fp8 T*3072 (qkvb dead)
    unsigned short* qkv_wt  = (unsigned short*)(wsb + 251658240);    // bf16 [2304,768] 3,538,944
    unsigned short* proj_wt = (unsigned short*)(wsb + 255197184);    // bf16 [768,768]  1,179,648
    unsigned char*  fc1_wf8 = (unsigned char*)(wsb + 256376832);     // fp8 [3072,768]  2,359,296
    unsigned char*  fc2_wf8 = (unsigned char*)(wsb + 261095424);     // fp8 [768,3072]  2,359,296
    unsigned short* xln     = (unsigned short*)d_out;                // bf16 T*768 in d_out (free until step 5)

    // 0) weight prep
    wconv<<<dim3(2304 / 32, 768 / 32), 256, 0, stream>>>(qkv_w, qkv_wt, DIMD, 2304);
    wconv<<<dim3(768 / 32, 768 / 32), 256, 0, stream>>>(proj_w, proj_wt, DIMD, DIMD);
    wconv_f8<<<dim3(3072 / 32, 768 / 32), 256, 0, stream>>>(fc1_w, fc1_wf8, DIMD, HIDDEN);
    wconv_f8<<<dim3(768 / 32, 3072 / 32), 256, 0, stream>>>(fc2_w, fc2_wf8, HIDDEN, DIMD);
    wprep<<<dim3(MFEAT / 32, HDIM / 32, HEADS), 256, 0, stream>>>(w_orf, worf_ts);
    // 1) xln = LN1(x) (bf16, in d_out)
    ln_vec<1><<<NTOK, 256, 0, stream>>>(x, ln1_g, ln1_b, xln);
    // 2) qkv = xln @ qkv_w + qkv_b (bf16, BK=64)
    gemm_bk64<0, false, true><<<dim3(2304 / 128, NTOK / 128), 256, 0, stream>>>(
        xln, qkv_wt, qkv_b, nullptr, qkvb, DIMD, 2304);
    // 3) phase A: ktvT (incl. ksum row)
    ktv_mfma<<<dim3(HEADS, BATCH), 256, 0, stream>>>(qkvb, worf_ts, ktvT);
    // 4) phase B: attn out (bf16)
    attn_out_mfma<<<dim3(SEQ / 128, HEADS, BATCH), 256, 0, stream>>>(
        qkvb, worf_ts, ktvT, attn);
    // 5) h = x + attn @ proj_w + proj_b -> d_out (f32, BK=32 3-buf)
    gemm_bk32<0, true, false><<<dim3(DIMD / 128, NTOK / 128), 256, 0, stream>>>(
        attn, proj_wt, proj_b, x, out, DIMD, DIMD);
    // 6) y2f8 = LN2(h) (fp8 kp128; ktvT/worf_ts dead)
    ln_vec<2><<<NTOK, 256, 0, stream>>>(out, ln2_g, ln2_b, y2f8);
    // 7) hidf8 = gelu(y2f8 @ fc1_w + fc1_b) (MX GEMM, fp8 kp128 out)
    gemm_mx<1, false, 2><<<dim3(HIDDEN / 128, NTOK / 128), 256, 0, stream>>>(
        y2f8, fc1_wf8, fc1_b, nullptr, hidf8, DIMD, HIDDEN);
    // 8) out = h + hidf8 @ fc2_w + fc2_b (MX GEMM, in-place residual)
    gemm_mx<0, true, 0><<<dim3(DIMD / 128, NTOK / 128), 256, 0, stream>>>(
        hidf8, fc2_wf8, fc2_b, out, out, HIDDEN, DIMD);
}